// Round 8
// baseline (781.980 us; speedup 1.0000x reference)
//
#include <hip/hip_runtime.h>
#include <cstddef>

#define T_STEPS 24
#define F_IN 64
#define H_DIM 128
#define ROWS 48
#define NRT 3
#define TOTAL_ROWS 20800
#define NUM_BLOCKS 434   // ceil(20800 / 48); last block has 16 valid rows

typedef _Float16 f16;
typedef _Float16 half8 __attribute__((ext_vector_type(8)));
typedef float floatx4 __attribute__((ext_vector_type(4)));

#define MFMA16(acc, a, b) (acc) = __builtin_amdgcn_mfma_f32_16x16x32_f16((a), (b), (acc), 0, 0, 0)

// Saturation-safe fast activations (+-inf -> correct limits, no NaN, no clamps).
__device__ __forceinline__ float sigm(float v) {
    return __builtin_amdgcn_rcpf(1.f + __builtin_amdgcn_exp2f(v * -1.44269504f));
}
__device__ __forceinline__ float tanh_(float v) {
    return 1.f - 2.f * __builtin_amdgcn_rcpf(1.f + __builtin_amdgcn_exp2f(v * 2.88539008f));
}

__global__ void cvt_f32_f16(const float* __restrict__ src, f16* __restrict__ dst, int n) {
    int i = blockIdx.x * 256 + threadIdx.x;
    if (i < n) dst[i] = (f16)src[i];
}

// Round 8 = round 7 + LOOP ROTATION (hand software-pipelining).
// hipcc does not schedule across the loop backedge, so in r7 the trans-heavy Seg4
// epilogue (12x sigm/tanh + global store) had nothing to overlap. Seg2(t+1) is
// independent of Seg4(t) (disjoint LDS buffers), so the loop is rotated to:
//   prologue Seg2(0);  loop: B2 | Seg3(t) | B3 | [ Seg4(t) ; Seg2(t+1) ]
// The merged barrier-free region has 102 MFMAs + both epilogues -> Seg2's MFMAs and
// ds_reads hide Seg4's trans chain + out[] store latency, and vice versa.
// Hazard audit (buffers, with P = t&1):
//   sH0: Seg2(t) writes buf[!P]; read by Seg3(t)/Seg4(t) after B2(t) and by
//        Seg2(t+1) (same region as Seg4(t), read-read with Seg4 - safe). Seg2(t+1)
//        writes buf[P] - last read by Seg2(t) two barriers earlier. OK.
//   sH1: Seg4(t) writes buf[!P]; read by Seg3(t+1) after B2(t+1) and Seg4(t+1)
//        after B3(t+1). Write of buf[P] at Seg4(t+1): last read Seg4(t) gZ, two
//        barriers earlier. OK.
//   sRH: written Seg3(t) before B3(t); read Seg4(t); next write Seg3(t+1) after
//        B2(t+1) - one barrier after last read. OK.
//   sX:  read by Seg2(t) (region t-1 / prologue); written for t+1 in Seg3(t)
//        (B2(t) between); read by Seg2(t+1) (B3(t) between). OK.
// Two barriers/step; all weights persistent (168 VGPR/lane, r7-proven spill-free).
#define SEG2(HR, HW)                                                                  \
    {                                                                                 \
        _Pragma("unroll")                                                             \
        for (int rt = 0; rt < NRT; ++rt) {                                            \
            floatx4 aR = (floatx4){0.f, 0.f, 0.f, 0.f};                               \
            floatx4 aZ = aR, aIN = aR, aHN = aR;                                      \
            _Pragma("unroll")                                                         \
            for (int kc = 0; kc < 2; ++kc) {                                          \
                const half8 ax = *(const half8*)&sX[rt * 16 + p][kc * 32 + ko];       \
                MFMA16(aR,  ax, Wih[0][kc]);                                          \
                MFMA16(aZ,  ax, Wih[1][kc]);                                          \
                MFMA16(aIN, ax, Wih[2][kc]);                                          \
            }                                                                         \
            _Pragma("unroll")                                                         \
            for (int kc = 0; kc < 4; ++kc) {                                          \
                const half8 ah = *(const half8*)&(HR)[rt * 16 + p][kc * 32 + ko];     \
                MFMA16(aR,  ah, Whh[0][kc]);                                          \
                MFMA16(aZ,  ah, Whh[1][kc]);                                          \
                MFMA16(aHN, ah, Whh[2][kc]);                                          \
            }                                                                         \
            _Pragma("unroll")                                                         \
            for (int i = 0; i < 4; ++i) {                                             \
                const float r  = sigm(aR[i] + bR);                                    \
                const float z  = sigm(aZ[i] + bZ);                                    \
                const float n  = tanh_(aIN[i] + bIN + r * (aHN[i] + bHN));            \
                const float h0 = n + z * (h0p[rt][i] - n);                            \
                h0p[rt][i] = h0;                                                      \
                (HW)[rt * 16 + quad * 4 + i][c] = (f16)h0;                            \
            }                                                                         \
        }                                                                             \
    }

__global__ __launch_bounds__(512, 2) void gru_fused(
    const float* __restrict__ x,
    const float* __restrict__ b_ih, const float* __restrict__ b_hh,
    const float* __restrict__ gate_b, const float* __restrict__ out_b,
    const f16* __restrict__ wih, const f16* __restrict__ whh,
    const f16* __restrict__ gw, const f16* __restrict__ ow,
    float* __restrict__ out)
{
    __shared__ f16 sX[ROWS][72];       // x_t tile (written for t+1 in Seg3)
    __shared__ f16 sH0a[ROWS][136];    // h0 double buffer
    __shared__ f16 sH0b[ROWS][136];
    __shared__ f16 sH1a[ROWS][136];    // h1 double buffer
    __shared__ f16 sH1b[ROWS][136];
    __shared__ f16 sRH[ROWS][136];     // r * h1_old

    const int tid  = threadIdx.x;
    const int lane = tid & 63;
    const int wv   = tid >> 6;      // 0..7 -> column tile
    const int p    = lane & 15;     // col-in-tile (B frag) / row-in-tile (A frag)
    const int quad = lane >> 4;     // 0..3
    const int ko   = quad * 8;      // k-offset within a K=32 chunk
    const int c    = wv * 16 + p;   // global output column 0..127
    const int row0 = blockIdx.x * ROWS;
    const bool full = (row0 + ROWS) <= TOTAL_ROWS;

    // x staging: 384 threads (waves 0..5), 8 floats each -> 48 rows x 64 floats
    const int srr = tid >> 3;
    const int sf8 = (tid & 7) * 8;
    int xgr = row0 + srr;
    if (xgr > TOTAL_ROWS - 1) xgr = TOTAL_ROWS - 1;
    const float* xsrc = x + (size_t)xgr * (T_STEPS * F_IN) + sf8;

    // zero-init state buffers read at t=0
    for (int i = tid; i < (ROWS * 136) / 2; i += 512) {
        ((unsigned int*)&sH0a[0][0])[i] = 0u;
        ((unsigned int*)&sH1a[0][0])[i] = 0u;
    }

    // per-column biases
    const float bR  = b_ih[c] + b_hh[c];
    const float bZ  = b_ih[128 + c] + b_hh[128 + c];
    const float bIN = b_ih[256 + c];
    const float bHN = b_hh[256 + c];
    const float bGR = gate_b[c];
    const float bGZ = gate_b[128 + c];
    const float bO  = out_b[c];

    // ---- weight-stationary B fragments, ALL persistent (n = c, k = kc*32+quad*8+j) ----
    half8 Wih[3][2], Whh[3][4], Wgw[2][8], Wow[8];
    #pragma unroll
    for (int g = 0; g < 3; ++g) {
        #pragma unroll
        for (int kc = 0; kc < 2; ++kc)
            Wih[g][kc] = *(const half8*)(wih + (size_t)(g * 128 + c) * 64 + kc * 32 + ko);
        #pragma unroll
        for (int kc = 0; kc < 4; ++kc)
            Whh[g][kc] = *(const half8*)(whh + (size_t)(g * 128 + c) * 128 + kc * 32 + ko);
    }
    #pragma unroll
    for (int g = 0; g < 2; ++g)
        #pragma unroll
        for (int kc = 0; kc < 8; ++kc)
            Wgw[g][kc] = *(const half8*)(gw + (size_t)(g * 128 + c) * 256 + kc * 32 + ko);
    #pragma unroll
    for (int kc = 0; kc < 8; ++kc)
        Wow[kc] = *(const half8*)(ow + (size_t)c * 256 + kc * 32 + ko);

    // recurrent state, fp32 regs: element i -> row rt*16 + quad*4 + i, col c
    floatx4 h0p[NRT], h1p[NRT];
    #pragma unroll
    for (int rt = 0; rt < NRT; ++rt) {
        h0p[rt] = (floatx4){0.f, 0.f, 0.f, 0.f};
        h1p[rt] = (floatx4){0.f, 0.f, 0.f, 0.f};
    }

    // stage x(t=0)
    if (tid < 384) {
        const floatx4 v0 = *(const floatx4*)(xsrc);
        const floatx4 v1 = *(const floatx4*)(xsrc + 4);
        half8 h;
        h[0] = (f16)v0[0]; h[1] = (f16)v0[1]; h[2] = (f16)v0[2]; h[3] = (f16)v0[3];
        h[4] = (f16)v1[0]; h[5] = (f16)v1[1]; h[6] = (f16)v1[2]; h[7] = (f16)v1[3];
        *(half8*)&sX[srr][sf8] = h;
    }
    __syncthreads();

    // ---- prologue: Seg2(0): reads sH0a (zero), writes sH0b ----
    SEG2(sH0a, sH0b);

    for (int t = 0; t < T_STEPS; ++t) {
        const f16 (*sH0w_t)[136] = (t & 1) ? sH0a : sH0b;  // h0(t), written by Seg2(t)
        const f16 (*sH1r_t)[136] = (t & 1) ? sH1b : sH1a;  // h1(t-1)
        f16 (*sH1w_t)[136]       = (t & 1) ? sH1a : sH1b;  // h1(t)

        __syncthreads();   // B2(t): h0(t) visible; orders Seg4(t-1) sH1-writes vs Seg3 reads,
                           // Seg4(t-1) sRH-reads vs Seg3 writes, Seg2(t) sX-reads vs x-store

        // ---- Seg3(t): issue x(t+1) loads; gR GEMM; write sRH; store x(t+1) -> sX ----
        floatx4 px0, px1;
        if (t < T_STEPS - 1 && tid < 384) {
            px0 = *(const floatx4*)(xsrc + (t + 1) * F_IN);
            px1 = *(const floatx4*)(xsrc + (t + 1) * F_IN + 4);
        }
        #pragma unroll
        for (int rt = 0; rt < NRT; ++rt) {
            floatx4 gR = (floatx4){0.f, 0.f, 0.f, 0.f};
            #pragma unroll
            for (int kc = 0; kc < 4; ++kc) {
                const half8 a1 = *(const half8*)&sH1r_t[rt * 16 + p][kc * 32 + ko];
                MFMA16(gR, a1, Wgw[0][4 + kc]);
            }
            #pragma unroll
            for (int kc = 0; kc < 4; ++kc) {
                const half8 a0 = *(const half8*)&sH0w_t[rt * 16 + p][kc * 32 + ko];
                MFMA16(gR, a0, Wgw[0][kc]);
            }
            #pragma unroll
            for (int i = 0; i < 4; ++i) {
                const float r1 = sigm(gR[i] + bGR);
                sRH[rt * 16 + quad * 4 + i][c] = (f16)(r1 * h1p[rt][i]);
            }
        }
        if (t < T_STEPS - 1 && tid < 384) {
            half8 h;
            h[0] = (f16)px0[0]; h[1] = (f16)px0[1]; h[2] = (f16)px0[2]; h[3] = (f16)px0[3];
            h[4] = (f16)px1[0]; h[5] = (f16)px1[1]; h[6] = (f16)px1[2]; h[7] = (f16)px1[3];
            *(half8*)&sX[srr][sf8] = h;
        }
        __syncthreads();   // B3(t): sRH and sX(t+1) visible

        // ---- merged region: Seg4(t) ; Seg2(t+1) (barrier-free, cross-step ILP) ----
        #pragma unroll
        for (int rt = 0; rt < NRT; ++rt) {
            floatx4 gZ = (floatx4){0.f, 0.f, 0.f, 0.f};
            floatx4 aC = gZ;
            #pragma unroll
            for (int kc = 0; kc < 4; ++kc) {
                const half8 a1 = *(const half8*)&sH1r_t[rt * 16 + p][kc * 32 + ko];
                MFMA16(gZ, a1, Wgw[1][4 + kc]);
            }
            #pragma unroll
            for (int kc = 0; kc < 4; ++kc) {
                const half8 a0 = *(const half8*)&sH0w_t[rt * 16 + p][kc * 32 + ko];
                MFMA16(gZ, a0, Wgw[1][kc]);
                MFMA16(aC, a0, Wow[kc]);
            }
            #pragma unroll
            for (int kc = 0; kc < 4; ++kc) {
                const half8 ar = *(const half8*)&sRH[rt * 16 + p][kc * 32 + ko];
                MFMA16(aC, ar, Wow[4 + kc]);
            }
            #pragma unroll
            for (int i = 0; i < 4; ++i) {
                const float zz = sigm(gZ[i] + bGZ);
                const float cd = tanh_(aC[i] + bO);
                const float hv = cd + zz * (h1p[rt][i] - cd);
                h1p[rt][i] = hv;
                sH1w_t[rt * 16 + quad * 4 + i][c] = (f16)hv;
                const int grow = row0 + rt * 16 + quad * 4 + i;
                if (full || grow < TOTAL_ROWS)
                    out[((size_t)grow * T_STEPS + t) * H_DIM + c] = hv;
            }
        }
        if (t < T_STEPS - 1) {
            // Seg2(t+1): reads sX(t+1) and sH0w_t; writes the other sH0 buffer.
            if (t & 1) { SEG2(sH0a, sH0b); } else { SEG2(sH0b, sH0a); }
        }
        // no trailing barrier: B2(t+1) publishes h0(t+1) and h1(t)
    }
}

extern "C" void kernel_launch(void* const* d_in, const int* in_sizes, int n_in,
                              void* d_out, int out_size, void* d_ws, size_t ws_size,
                              hipStream_t stream) {
    (void)in_sizes; (void)n_in; (void)out_size; (void)ws_size;
    const float* x      = (const float*)d_in[0];
    const float* w_ih   = (const float*)d_in[1];
    const float* w_hh   = (const float*)d_in[2];
    const float* b_ih   = (const float*)d_in[3];
    const float* b_hh   = (const float*)d_in[4];
    const float* gate_w = (const float*)d_in[5];
    const float* gate_b = (const float*)d_in[6];
    const float* out_w  = (const float*)d_in[7];
    const float* out_b  = (const float*)d_in[8];

    f16* wsH = (f16*)d_ws;
    f16* wih = wsH;                 // 384*64   = 24576 halves
    f16* whh = wsH + 24576;         // 384*128  = 49152
    f16* gw  = wsH + 73728;         // 256*256  = 65536
    f16* ow  = wsH + 139264;        // 128*256  = 32768

    cvt_f32_f16<<<(24576 + 255) / 256, 256, 0, stream>>>(w_ih, wih, 24576);
    cvt_f32_f16<<<(49152 + 255) / 256, 256, 0, stream>>>(w_hh, whh, 49152);
    cvt_f32_f16<<<(65536 + 255) / 256, 256, 0, stream>>>(gate_w, gw, 65536);
    cvt_f32_f16<<<(32768 + 255) / 256, 256, 0, stream>>>(out_w, ow, 32768);

    gru_fused<<<NUM_BLOCKS, 512, 0, stream>>>(x, b_ih, b_hh, gate_b, out_b,
                                              wih, whh, gw, ow, (float*)d_out);
}